// Round 1
// baseline (417.238 us; speedup 1.0000x reference)
//
#include <hip/hip_runtime.h>

// ViewMorphing forward — MI355X (gfx950)
// out[0 .. 3*N*HW-1] = warped+masked image sum, out[3*N*HW] = oob loss scalar.

constexpr int D    = 512;
constexpr int HW   = D * D;            // 262144 = 2^18
constexpr int NB   = 32;
constexpr int NPIX = NB * HW;          // 8,388,608
// loss scale: 0.01 / (N*2*HW) / (D*D)
constexpr float LOSS_SCALE = (float)(0.01 / (2.0 * (double)NPIX * (double)HW));

__device__ __forceinline__ float3 sample_img(const float* __restrict__ im,
                                             float q0o, float q1o, float& oob)
{
    // clip like jnp.clip(qi_orig, 0.001, D-1.001)
    const float hi = (float)(512.0 - 1.001);   // 510.999f
    float q0 = fminf(fmaxf(q0o, 0.001f), hi);
    float q1 = fminf(fmaxf(q1o, 0.001f), hi);
    float d0 = q0o - q0, d1 = q1o - q1;
    oob += d0 * d0 + d1 * d1;

    float fx = floorf(q0), fy = floorf(q1);
    float cx = ceilf(q0),  cy = ceilf(q1);
    // w = (1 - |q0 - nbx|) * (1 - |q1 - nby|)
    float wfx = 1.0f - (q0 - fx), wcx = 1.0f - (cx - q0);
    float wfy = 1.0f - (q1 - fy), wcy = 1.0f - (cy - q1);

    int ix0 = (int)fx, iy0 = (int)fy, ix1 = (int)cx, iy1 = (int)cy;
    // ind = y + D*x
    int iff = iy0 + D * ix0;
    int icf = iy0 + D * ix1;
    int ifc = iy1 + D * ix0;
    int icc = iy1 + D * ix1;

    float wff = wfx * wfy, wcf = wcx * wfy, wfc = wfx * wcy, wcc = wcx * wcy;

    float3 r;
    r.x = wff * im[iff]          + wcf * im[icf]          + wfc * im[ifc]          + wcc * im[icc];
    r.y = wff * im[HW + iff]     + wcf * im[HW + icf]     + wfc * im[HW + ifc]     + wcc * im[HW + icc];
    r.z = wff * im[2 * HW + iff] + wcf * im[2 * HW + icf] + wfc * im[2 * HW + ifc] + wcc * im[2 * HW + icc];
    return r;
}

__global__ void __launch_bounds__(256)
vm_fwd(const float* __restrict__ im1, const float* __restrict__ im2,
       const float* __restrict__ C,   const float* __restrict__ M1,
       const float* __restrict__ M2,  float* __restrict__ out)
{
    float oob = 0.0f;
    int stride = gridDim.x * blockDim.x;
    for (int idx = blockIdx.x * blockDim.x + threadIdx.x; idx < NPIX; idx += stride) {
        int n  = idx >> 18;          // / HW
        int hw = idx & (HW - 1);
        float qx = (float)(hw >> 9);     // row
        float qy = (float)(hw & (D - 1)); // col

        const float* Cn = C + (size_t)n * 2 * HW;
        float c0 = Cn[hw];
        float c1 = Cn[HW + hw];
        float m1 = M1[idx];
        float m2 = M2[idx];

        const float* p1 = im1 + (size_t)n * 3 * HW;
        const float* p2 = im2 + (size_t)n * 3 * HW;

        float3 a = sample_img(p1, qx + c0, qy + c1, oob);
        float3 b = sample_img(p2, qx - c0, qy - c1, oob);

        size_t obase = (size_t)n * 3 * HW + hw;
        out[obase]          = a.x * m1 + b.x * m2;
        out[obase + HW]     = a.y * m1 + b.y * m2;
        out[obase + 2 * HW] = a.z * m1 + b.z * m2;
    }

    // block-level reduction of oob, then one atomic per block
    #pragma unroll
    for (int off = 32; off > 0; off >>= 1)
        oob += __shfl_down(oob, off, 64);

    __shared__ float wave_sums[4];   // 256 threads / wave64
    int lane = threadIdx.x & 63;
    int wave = threadIdx.x >> 6;
    if (lane == 0) wave_sums[wave] = oob;
    __syncthreads();
    if (threadIdx.x == 0) {
        float s = wave_sums[0] + wave_sums[1] + wave_sums[2] + wave_sums[3];
        atomicAdd(out + (size_t)3 * NPIX, s * LOSS_SCALE);
    }
}

extern "C" void kernel_launch(void* const* d_in, const int* in_sizes, int n_in,
                              void* d_out, int out_size, void* d_ws, size_t ws_size,
                              hipStream_t stream) {
    const float* im1 = (const float*)d_in[0];
    const float* im2 = (const float*)d_in[1];
    const float* C   = (const float*)d_in[2];
    const float* M1  = (const float*)d_in[3];
    const float* M2  = (const float*)d_in[4];
    float* out = (float*)d_out;

    // zero the loss scalar (harness poisons d_out with 0xAA before every launch)
    hipMemsetAsync(out + (size_t)3 * NPIX, 0, sizeof(float), stream);

    vm_fwd<<<8192, 256, 0, stream>>>(im1, im2, C, M1, M2, out);
}